// Round 1
// baseline (244.352 us; speedup 1.0000x reference)
//
#include <hip/hip_runtime.h>

// Problem constants (fixed shapes from setup_inputs)
#define HH 96
#define WW 96
#define NN (HH * WW)   // 9216 pixels
#define NB 2           // batch
#define NC 21          // value channels
#define NCI 3          // image channels

constexpr float INV_TA = 1.0f / 8.0f;  // 1/theta_alpha
constexpr float INV_TB = 1.0f / 0.5f;  // 1/theta_beta

constexpr int JC    = 32;          // j-chunks per (b, i-tile)  -> parallelism
constexpr int JT    = NN / JC;     // 288 j's per chunk
constexpr int MI    = 4;           // i-pixels per thread
constexpr int BLK   = 256;         // threads per block
constexpr int ITILE = BLK * MI;    // 1024 i's per block
constexpr int ITILES = NN / ITILE; // 9

__global__ void zero_out_kernel(float* __restrict__ out, int n) {
    int i = blockIdx.x * blockDim.x + threadIdx.x;
    if (i < n) out[i] = 0.0f;
}

__global__ __launch_bounds__(BLK, 1)
void perm_gauss_kernel(const float* __restrict__ cur,   // [B, NC, N]
                       const float* __restrict__ img,   // [B, NCI, N]
                       float* __restrict__ out) {       // [B, NC, N]
    // LDS: j-tile features (f0..f4, ej=-0.5*|fj|^2, pad, pad) and 21 channel
    // values (padded to 24 for float4 reads). All inner-loop reads are
    // wave-uniform addresses -> LDS broadcast, conflict-free.
    __shared__ float fjs[JT][8];
    __shared__ float vjs[JT][24];

    const int tid   = threadIdx.x;
    const int jc    = blockIdx.x;   // j-chunk
    const int it    = blockIdx.y;   // i-tile
    const int b     = blockIdx.z;   // batch
    const int ibase = it * ITILE;
    const int jbase = jc * JT;

    const float* curb = cur + (size_t)b * NC * NN;
    const float* imgb = img + (size_t)b * NCI * NN;

    // ---- stage j-chunk into LDS (coalesced per channel-plane) ----
    for (int jl = tid; jl < JT; jl += BLK) {
        const int jg = jbase + jl;
        const float y = (float)(jg / WW);
        const float x = (float)(jg % WW);
        const float f0 = y * INV_TA;
        const float f1 = x * INV_TA;
        const float f2 = imgb[0 * NN + jg] * INV_TB;
        const float f3 = imgb[1 * NN + jg] * INV_TB;
        const float f4 = imgb[2 * NN + jg] * INV_TB;
        const float ej = -0.5f * (f0 * f0 + f1 * f1 + f2 * f2 + f3 * f3 + f4 * f4);
        fjs[jl][0] = f0; fjs[jl][1] = f1; fjs[jl][2] = f2; fjs[jl][3] = f3;
        fjs[jl][4] = f4; fjs[jl][5] = ej; fjs[jl][6] = 0.0f; fjs[jl][7] = 0.0f;
        #pragma unroll
        for (int c = 0; c < NC; ++c)
            vjs[jl][c] = curb[(size_t)c * NN + jg];
        vjs[jl][21] = 0.0f; vjs[jl][22] = 0.0f; vjs[jl][23] = 0.0f;
    }

    // ---- per-thread i features (coalesced loads) ----
    float fi[MI][5];
    float ei[MI];
    #pragma unroll
    for (int k = 0; k < MI; ++k) {
        const int i = ibase + k * BLK + tid;
        const float y = (float)(i / WW);
        const float x = (float)(i % WW);
        fi[k][0] = y * INV_TA;
        fi[k][1] = x * INV_TA;
        fi[k][2] = imgb[0 * NN + i] * INV_TB;
        fi[k][3] = imgb[1 * NN + i] * INV_TB;
        fi[k][4] = imgb[2 * NN + i] * INV_TB;
        ei[k] = -0.5f * (fi[k][0] * fi[k][0] + fi[k][1] * fi[k][1] +
                         fi[k][2] * fi[k][2] + fi[k][3] * fi[k][3] +
                         fi[k][4] * fi[k][4]);
    }

    float acc[MI][NC];
    #pragma unroll
    for (int k = 0; k < MI; ++k)
        #pragma unroll
        for (int c = 0; c < NC; ++c)
            acc[k][c] = 0.0f;

    __syncthreads();

    // ---- main loop: w_ij = exp(fi.fj - 0.5|fi|^2 - 0.5|fj|^2) ----
    for (int jl = 0; jl < JT; ++jl) {
        const float4 fa = *(const float4*)&fjs[jl][0];  // f0..f3
        const float4 fb = *(const float4*)&fjs[jl][4];  // f4, ej, pad, pad
        float vv[24];
        *(float4*)&vv[0]  = *(const float4*)&vjs[jl][0];
        *(float4*)&vv[4]  = *(const float4*)&vjs[jl][4];
        *(float4*)&vv[8]  = *(const float4*)&vjs[jl][8];
        *(float4*)&vv[12] = *(const float4*)&vjs[jl][12];
        *(float4*)&vv[16] = *(const float4*)&vjs[jl][16];
        *(float4*)&vv[20] = *(const float4*)&vjs[jl][20];

        #pragma unroll
        for (int k = 0; k < MI; ++k) {
            float arg = ei[k] + fb.y;
            arg += fi[k][0] * fa.x;
            arg += fi[k][1] * fa.y;
            arg += fi[k][2] * fa.z;
            arg += fi[k][3] * fa.w;
            arg += fi[k][4] * fb.x;
            const float w = __expf(arg);
            #pragma unroll
            for (int c = 0; c < NC; ++c)
                acc[k][c] += w * vv[c];
        }
    }

    // ---- epilogue: coalesced atomic accumulation (JC partials/address) ----
    #pragma unroll
    for (int k = 0; k < MI; ++k) {
        const int i = ibase + k * BLK + tid;
        #pragma unroll
        for (int c = 0; c < NC; ++c)
            atomicAdd(&out[((size_t)b * NC + c) * NN + i], acc[k][c]);
    }
}

extern "C" void kernel_launch(void* const* d_in, const int* in_sizes, int n_in,
                              void* d_out, int out_size, void* d_ws, size_t ws_size,
                              hipStream_t stream) {
    const float* cur = (const float*)d_in[0];  // cur_state  [2,21,96,96]
    const float* img = (const float*)d_in[1];  // input_image [2,3,96,96]
    float* out = (float*)d_out;                // [2,21,96,96]

    // d_out is poisoned with 0xAA before every timed launch -> zero it first.
    const int total = NB * NC * NN;
    zero_out_kernel<<<(total + BLK - 1) / BLK, BLK, 0, stream>>>(out, total);

    dim3 grid(JC, ITILES, NB);  // 32 x 9 x 2 = 576 blocks
    perm_gauss_kernel<<<grid, BLK, 0, stream>>>(cur, img, out);
}

// Round 2
// 141.074 us; speedup vs baseline: 1.7321x; 1.7321x over previous
//
#include <hip/hip_runtime.h>
#include <hip/hip_bf16.h>

// Bilateral Gaussian filter: out[b,c,i] = sum_j exp(-0.5|f_i-f_j|^2) * cur[b,c,j]
// f = [y/8, x/8, r/.5, g/.5, b/.5]  (D=5).  B=2, C=21, N=9216.
//
// Flash-style: fp32 VALU computes w_ij = exp(fi.fj + ei + ej) directly in
// MFMA A-fragment layout (lane l owns W[m=l&31][k=(l>>5)*8+t]); V staged in
// LDS in B-fragment layout; v_mfma_f32_32x32x16_bf16 accumulates 32i x 32c
// (21 used) in fp32 AGPRs.  Grid split over j for parallelism; partials
// combined with atomicAdd after a per-wave LDS transpose (coalesced).

#define HH 96
#define WW 96
#define NN (HH * WW)   // 9216
#define NB 2
#define NC 21

typedef __attribute__((ext_vector_type(8))) short short8;
typedef __attribute__((ext_vector_type(16))) float f32x16;

constexpr float INV_TA = 0.125f;  // 1/theta_alpha
constexpr float INV_TB = 2.0f;    // 1/theta_beta

constexpr int BLK = 256;          // 4 waves
constexpr int ITILE = 64;         // i per block (2 subtiles of 32, waves pair up)
constexpr int NIT = NN / ITILE;   // 144 i-tiles
constexpr int G = 8;              // j-groups (grid parallelism)
constexpr int JG = NN / G;        // 1152 j per group
constexpr int JS = 288;           // j staged per piece
constexpr int NP = JG / JS;       // 4 pieces
constexpr int NCHUNK = JS / 16;   // 18 chunks of 16 j per piece

// LDS layout (aliased):
//  [0, 18432)           V bf16 [jblk=36][c=32][jj=8]   (B-fragment friendly)
//  [18432, 25536)       features fp32 [6][296]          (f0..f4, ej; transposed)
//  epilogue (after barrier, aliased at 0): tile fp32 [4 waves][32][33]
constexpr int FS = JS + 8;                     // 296 (row stride, 16B-aligned base)
constexpr int VLDS_ELEMS = (JS / 8) * 32 * 8;  // 9216 bf16 = 18432 B
constexpr int SMEM_BYTES = VLDS_ELEMS * 2 + 6 * FS * 4;  // 25536 B

__global__ void zero_out_kernel(float* __restrict__ out, int n) {
    int i = blockIdx.x * blockDim.x + threadIdx.x;
    if (i < n) out[i] = 0.0f;
}

__global__ __launch_bounds__(BLK)
void perm_gauss_mfma(const float* __restrict__ cur,   // [B, NC, N]
                     const float* __restrict__ img,   // [B, 3, N]
                     float* __restrict__ out) {       // [B, NC, N]
    __shared__ __align__(16) char smem[SMEM_BYTES];
    __hip_bfloat16* vlds = (__hip_bfloat16*)smem;
    float* flds = (float*)(smem + VLDS_ELEMS * 2);
    float* tile = (float*)smem;  // epilogue alias, [wave][32][33]

    const int tid   = threadIdx.x;
    const int lane  = tid & 63;
    const int wave  = tid >> 6;
    const int isub  = wave & 1;   // which 32-i subtile
    const int jpart = wave >> 1;  // which half of the chunks
    const int il    = lane & 31;  // i-local (A-frag m, also D col index c)
    const int half  = lane >> 5;  // k-offset selector

    const int it = blockIdx.x;    // i-tile
    const int g  = blockIdx.y;    // j-group
    const int b  = blockIdx.z;    // batch

    const int ibase = it * ITILE;
    const float* curb = cur + (size_t)b * NC * NN;
    const float* imgb = img + (size_t)b * 3 * NN;
    float* outb = out + (size_t)b * NC * NN;

    // ---- per-lane i features (fp32) ----
    const int ig = ibase + isub * 32 + il;
    float fi0 = (float)(ig / WW) * INV_TA;
    float fi1 = (float)(ig % WW) * INV_TA;
    float fi2 = imgb[ig] * INV_TB;
    float fi3 = imgb[NN + ig] * INV_TB;
    float fi4 = imgb[2 * NN + ig] * INV_TB;
    float ei = -0.5f * (fi0 * fi0 + fi1 * fi1 + fi2 * fi2 + fi3 * fi3 + fi4 * fi4);

    f32x16 acc;
    #pragma unroll
    for (int r = 0; r < 16; ++r) acc[r] = 0.0f;

    const int jg0 = g * JG;
    for (int p = 0; p < NP; ++p) {
        __syncthreads();  // previous piece fully consumed
        // ---- stage piece p: 288 j's ----
        for (int t = tid; t < JS; t += BLK) {
            const int jg = jg0 + p * JS + t;
            const float y = (float)(jg / WW);
            const float x = (float)(jg % WW);
            const float f0 = y * INV_TA;
            const float f1 = x * INV_TA;
            const float f2 = imgb[jg] * INV_TB;
            const float f3 = imgb[NN + jg] * INV_TB;
            const float f4 = imgb[2 * NN + jg] * INV_TB;
            flds[0 * FS + t] = f0;
            flds[1 * FS + t] = f1;
            flds[2 * FS + t] = f2;
            flds[3 * FS + t] = f3;
            flds[4 * FS + t] = f4;
            flds[5 * FS + t] = -0.5f * (f0 * f0 + f1 * f1 + f2 * f2 +
                                        f3 * f3 + f4 * f4);
            // V in B-fragment layout: vlds[(j/8)*32 + c][j%8]
            __hip_bfloat16* vrow = vlds + (size_t)(t >> 3) * 32 * 8 + (t & 7);
            #pragma unroll
            for (int c = 0; c < NC; ++c)
                vrow[c * 8] = __float2bfloat16(curb[(size_t)c * NN + jg]);
        }
        __syncthreads();

        // ---- main loop: this wave's 9 chunks of 16 j ----
        for (int q = 0; q < NCHUNK / 2; ++q) {
            const int chunk = jpart + 2 * q;
            const int jb = chunk * 16;
            // fj features for my 8 j's (j = jb + half*8 + t) — broadcast reads
            float f[6][8];
            #pragma unroll
            for (int d = 0; d < 6; ++d) {
                *(float4*)&f[d][0] = *(const float4*)&flds[d * FS + jb + half * 8];
                *(float4*)&f[d][4] = *(const float4*)&flds[d * FS + jb + half * 8 + 4];
            }
            // B-fragment: V[k=jb+half*8+t][n=il]
            const short8 bfrag =
                *(const short8*)&vlds[((size_t)((jb >> 3) + half) * 32 + il) * 8];

            union { short8 v; unsigned short u[8]; } af;
            #pragma unroll
            for (int t = 0; t < 8; ++t) {
                float arg = ei + f[5][t];
                arg += fi0 * f[0][t];
                arg += fi1 * f[1][t];
                arg += fi2 * f[2][t];
                arg += fi3 * f[3][t];
                arg += fi4 * f[4][t];
                const float w = __expf(arg);
                const __hip_bfloat16 hb = __float2bfloat16(w);
                unsigned short us;
                __builtin_memcpy(&us, &hb, 2);
                af.u[t] = us;
            }
            acc = __builtin_amdgcn_mfma_f32_32x32x16_bf16(af.v, bfrag, acc, 0, 0, 0);
        }
    }

    // ---- epilogue: per-wave LDS transpose, then coalesced atomics ----
    __syncthreads();  // everyone done reading staged LDS (tile aliases it)
    float* mytile = tile + wave * 32 * 33;
    // D layout: col(c) = lane&31, row(i) = (r&3) + 8*(r>>2) + 4*half
    #pragma unroll
    for (int r = 0; r < 16; ++r) {
        const int row = (r & 3) + 8 * (r >> 2) + 4 * half;
        mytile[row * 33 + il] = acc[r];
    }
    // read transposed: lane -> (i = il, c = 2*cc + half), coalesced over i
    #pragma unroll
    for (int cc = 0; cc < 11; ++cc) {
        const int c = 2 * cc + half;
        if (c < NC) {
            const float v = mytile[il * 33 + c];
            atomicAdd(&outb[(size_t)c * NN + ibase + isub * 32 + il], v);
        }
    }
}

extern "C" void kernel_launch(void* const* d_in, const int* in_sizes, int n_in,
                              void* d_out, int out_size, void* d_ws, size_t ws_size,
                              hipStream_t stream) {
    const float* cur = (const float*)d_in[0];  // cur_state  [2,21,96,96]
    const float* img = (const float*)d_in[1];  // input_image [2,3,96,96]
    float* out = (float*)d_out;

    const int total = NB * NC * NN;
    zero_out_kernel<<<(total + BLK - 1) / BLK, BLK, 0, stream>>>(out, total);

    dim3 grid(NIT, G, NB);  // 144 x 8 x 2 = 2304 blocks
    perm_gauss_mfma<<<grid, BLK, 0, stream>>>(cur, img, out);
}